// Round 10
// baseline (875.829 us; speedup 1.0000x reference)
//
#include <hip/hip_runtime.h>
#include <hip/hip_bf16.h>

// ---------------------------------------------------------------------------
// QLayer: per-type 2-layer MLP.
//   h   = relu(x_t @ W1_t + b1_t)       [16384x512]@[512x1024]   (x4 types)
//   out = h @ W2_t + b2_t, padded to 128 cols                    (x4 types)
// Round 10: SINGLE-buffered LDS (GEMM1 64KB -> 2 blocks/CU, GEMM2 48KB ->
// 3 blocks/CU). Cross-block overlap (m114) replaces intra-block dbuf: while
// one block waits at its stage/publish barrier, the co-resident block's
// waves feed the MFMA pipe. Fused fp32->bf16 A path kept (fa reg pipeline
// 1 tile deep, counted vmcnt(8) keeps refills in flight across barriers).
// ---------------------------------------------------------------------------

typedef __attribute__((ext_vector_type(8))) short short8;
typedef __attribute__((ext_vector_type(4))) float f32x4;

#define NT 4
#define NNODE 16384
#define DIN 512
#define DH 1024
#define MAXO 128

static __device__ __forceinline__ ushort f2bf(float f) {
    __hip_bfloat16 h = __float2bfloat16(f);
    return *reinterpret_cast<ushort*>(&h);
}

static __device__ __forceinline__ short8 pack8(const float4 a, const float4 b) {
    union { short8 v; ushort u[8]; } r;
    r.u[0] = f2bf(a.x); r.u[1] = f2bf(a.y); r.u[2] = f2bf(a.z); r.u[3] = f2bf(a.w);
    r.u[4] = f2bf(b.x); r.u[5] = f2bf(b.y); r.u[6] = f2bf(b.z); r.u[7] = f2bf(b.w);
    return r.v;
}

#define GLD(gsrc, ldst)                                                        \
    __builtin_amdgcn_global_load_lds(                                          \
        (const __attribute__((address_space(1))) void*)(gsrc),                 \
        (__attribute__((address_space(3))) void*)(ldst), 16, 0, 0)

// --- W1 transpose+convert: in fp32 [R][Cin] -> out bf16 [Cout][R] ----------
__global__ __launch_bounds__(256) void cvt_w_t_kernel(
    const float* __restrict__ in, ushort* __restrict__ out,
    int R, int Cin, size_t in_tstride, size_t out_tstride) {
    __shared__ float tile[32][33];
    const int t = blockIdx.z;
    in += (size_t)t * in_tstride;
    out += (size_t)t * out_tstride;
    const int c0 = blockIdx.x * 32, r0 = blockIdx.y * 32;
    const int cx = threadIdx.x & 31;
    const int ry = threadIdx.x >> 5;   // 0..7
#pragma unroll
    for (int j = 0; j < 4; ++j) {
        int rr = ry + j * 8;
        int c = c0 + cx;
        tile[rr][cx] = (c < Cin) ? in[(size_t)(r0 + rr) * Cin + c] : 0.0f;
    }
    __syncthreads();
#pragma unroll
    for (int j = 0; j < 4; ++j) {
        int cc = ry + j * 8;
        out[(size_t)(c0 + cc) * R + r0 + cx] = f2bf(tile[cx][cc]);
    }
}

// --- W2 (all 4 types) transpose+convert + b2 pad, one launch ---------------
__global__ __launch_bounds__(256) void cvt_w2_kernel(
    const float* __restrict__ w0, const float* __restrict__ w1,
    const float* __restrict__ w2, const float* __restrict__ w3,
    const float* __restrict__ c0_, const float* __restrict__ c1_,
    const float* __restrict__ c2_, const float* __restrict__ c3_,
    ushort* __restrict__ out, float* __restrict__ b2p) {
    __shared__ float tile[32][33];
    const int t = blockIdx.z;
    const int Cin = (t == 0) ? 128 : (t == 1) ? 96 : (t == 2) ? 64 : 32;
    const float* in = (t == 0) ? w0 : (t == 1) ? w1 : (t == 2) ? w2 : w3;
    ushort* o = out + (size_t)t * MAXO * DH;
    const int c0 = blockIdx.x * 32, r0 = blockIdx.y * 32;
    const int cx = threadIdx.x & 31;
    const int ry = threadIdx.x >> 5;
#pragma unroll
    for (int j = 0; j < 4; ++j) {
        int rr = ry + j * 8;
        int c = c0 + cx;
        tile[rr][cx] = (c < Cin) ? in[(size_t)(r0 + rr) * Cin + c] : 0.0f;
    }
    __syncthreads();
#pragma unroll
    for (int j = 0; j < 4; ++j) {
        int cc = ry + j * 8;
        o[(size_t)(c0 + cc) * DH + r0 + cx] = f2bf(tile[cx][cc]);
    }
    if (blockIdx.x == 0 && blockIdx.y == 0 && threadIdx.x < 128) {
        const float* b = (t == 0) ? c0_ : (t == 1) ? c1_ : (t == 2) ? c2_ : c3_;
        const int n = threadIdx.x;
        b2p[t * 128 + n] = (n < Cin) ? b[n] : 0.0f;
    }
}

// ---------------------------------------------------------------------------
// Single-buffer 256-tile bf16 GEMM: C = A[M][K] * BT[N][K]^T + bias
// BM=256, BN in {256,128}, BK=64, 512 threads = 8 waves (WM=2, WN=4).
// Wave tile 128 x (BN/4). LDS: ONE buffer (A 32KB + B 32|16KB) -> 2|3
// blocks/CU. XOR-swizzle: byte(row,c16) = row*128 + ((c16*16)^((row&7)<<4)).
//
// Per K-tile i: { stage tile i [AFP32: B GLDs; pack8+ds_write fa(=tile i);
//   refill fa<-tile i+1 | !AFP32: A+B GLDs]; counted wait (vmcnt(8) keeps fa
//   refills flying / vmcnt(0) else) + lgkmcnt(0); s_barrier (publish);
//   compute (2x: frag ds_reads + 8*NF MFMA); s_barrier (free buffer) }.
// Stage latency inside a block is exposed by design: the co-resident
// block(s) on the CU compute through it (m114 cross-block overlap).
// MFMA operands swapped (D-row dim = n) -> vectorized epilogue stores.
// ---------------------------------------------------------------------------
template <int BN, bool AFP32, bool RELU, bool OUTBF16>
__global__ __launch_bounds__(512, 4) void gemms(
    const void* __restrict__ A0, const void* __restrict__ A1,
    const void* __restrict__ A2, const void* __restrict__ A3,
    const ushort* __restrict__ Bbase, const float* __restrict__ biasbase,
    void* __restrict__ Cbase, int N, int K, int MT,
    size_t strideA, size_t strideB, size_t strideBias, size_t strideC) {
    constexpr int NF = BN / 64;            // N-frags per wave (4 or 2)
    constexpr int NBC = BN * 8 / 512;      // B chunks per thread (4 or 2)
    constexpr int ABYTES = 256 * 64 * 2;   // 32 KB
    constexpr int BBYTES = BN * 64 * 2;    // 32 or 16 KB
    __shared__ char lds[ABYTES + BBYTES];  // single buffer
    static_assert(!AFP32 || NBC == 4, "AFP32 path assumes BN=256");

    // XCD-bijective block swizzle (grid % 8 == 0 by construction)
    const int cpx = gridDim.x >> 3;
    const int g = blockIdx.x;
    const int wg = (g & 7) * cpx + (g >> 3);
    const int NTL = N / BN;
    const int t = wg / (MT * NTL);
    const int rmn = wg % (MT * NTL);
    const int m0 = (rmn / NTL) * 256;
    const int n0 = (rmn % NTL) * BN;

    const float* Af = (const float*)((t == 0) ? A0 : (t == 1) ? A1
                                   : (t == 2) ? A2 : A3);        // AFP32
    const ushort* Ab = (const ushort*)A0 + (size_t)t * strideA;  // !AFP32
    const ushort* Bp = Bbase + (size_t)t * strideB;
    const float* bias = biasbase + (size_t)t * strideBias;

    const int tid = threadIdx.x;
    const int lane = tid & 63;
    const int w = tid >> 6;
    const int wm = w >> 2, wn = w & 3;     // WM=2, WN=4
    const int lrow = lane & 15, lgrp = lane >> 4;

    // --- staging addresses: 4 A chunks + NBC B chunks per thread -----------
    const float* af32src[4];               // AFP32: linear f32 src
    const ushort* abfsrc[4];               // !AFP32: pre-swizzled bf16 src
    int adst[4];                           // AFP32: swizzled dst; else linear
#pragma unroll
    for (int j = 0; j < 4; ++j) {
        const int c = j * 512 + tid;       // chunk 0..2047
        const int r = c >> 3;              // A row 0..255
        const int c8 = c & 7;
        const int cb = (c8 * 16) ^ ((r & 7) << 4);
        if (AFP32) {
            af32src[j] = Af + (size_t)(m0 + r) * K + c8 * 8;
            adst[j] = r * 128 + cb;        // swizzled dst for ds_write_b128
        } else {
            abfsrc[j] = Ab + (size_t)(m0 + r) * K + (cb >> 1);
            adst[j] = c * 16;              // linear dst for global_load_lds
        }
    }
    const ushort* bsrc[NBC];
    int bdst[NBC];
#pragma unroll
    for (int j = 0; j < NBC; ++j) {
        const int c = j * 512 + tid;       // chunk 0..BN*8-1
        const int r = c >> 3;              // B row 0..BN-1
        const int cb = ((c & 7) * 16) ^ ((r & 7) << 4);
        bsrc[j] = Bp + (size_t)(n0 + r) * K + (cb >> 1);
        bdst[j] = ABYTES + c * 16;
    }

    f32x4 acc[8][NF] = {};
    const int NK = K / 64;
    float4 fa[4][2];                       // fp32 A regs (AFP32 path)

    // --- prologue: prime fa with tile 0 (AFP32 only) -----------------------
    if (AFP32) {
#pragma unroll
        for (int j = 0; j < 4; ++j) {
            fa[j][0] = *reinterpret_cast<const float4*>(af32src[j]);
            fa[j][1] = *reinterpret_cast<const float4*>(af32src[j] + 4);
        }
    }

    for (int i = 0; i < NK; ++i) {
        const int kt = i * 64;
        const bool more = (i + 1 < NK);

        // ---- stage tile i into the single buffer (buffer is free here) ----
        if (AFP32) {
#pragma unroll
            for (int j = 0; j < NBC; ++j) GLD(bsrc[j] + kt, lds + bdst[j]);
            // publish fa (tile i data; landed: loaded >=1 compute phase ago)
#pragma unroll
            for (int j = 0; j < 4; ++j)
                *reinterpret_cast<short8*>(lds + adst[j]) =
                    pack8(fa[j][0], fa[j][1]);
            asm volatile("" ::: "memory");   // keep refill after ds_writes
            if (more) {
#pragma unroll
                for (int j = 0; j < 4; ++j) {
                    fa[j][0] = *reinterpret_cast<const float4*>(
                        af32src[j] + kt + 64);
                    fa[j][1] = *reinterpret_cast<const float4*>(
                        af32src[j] + kt + 68);
                }
                // retire B GLDs; the 8 fa refills (newest) stay in flight
                asm volatile("s_waitcnt vmcnt(8) lgkmcnt(0)" ::: "memory");
            } else {
                asm volatile("s_waitcnt vmcnt(0) lgkmcnt(0)" ::: "memory");
            }
        } else {
#pragma unroll
            for (int j = 0; j < 4; ++j) GLD(abfsrc[j] + kt, lds + adst[j]);
#pragma unroll
            for (int j = 0; j < NBC; ++j) GLD(bsrc[j] + kt, lds + bdst[j]);
            asm volatile("s_waitcnt vmcnt(0)" ::: "memory");
        }
        __builtin_amdgcn_s_barrier();        // publish tile i
        asm volatile("" ::: "memory");

        // ---- compute tile i ----
#pragma unroll
        for (int kkk = 0; kkk < 2; ++kkk) {
            short8 bfr[NF], af[8];
#pragma unroll
            for (int ni = 0; ni < NF; ++ni) {
                const int br = wn * (NF * 16) + ni * 16 + lrow;
                const int kb = (kkk * 64 + lgrp * 16) ^ ((br & 7) << 4);
                bfr[ni] = *(const short8*)(lds + ABYTES + br * 128 + kb);
            }
#pragma unroll
            for (int ml = 0; ml < 8; ++ml) {
                const int ar = wm * 128 + ml * 16 + lrow;
                const int kb = (kkk * 64 + lgrp * 16) ^ ((ar & 7) << 4);
                af[ml] = *(const short8*)(lds + ar * 128 + kb);
            }
#pragma unroll
            for (int ml = 0; ml < 8; ++ml)
#pragma unroll
                for (int ni = 0; ni < NF; ++ni)
                    acc[ml][ni] = __builtin_amdgcn_mfma_f32_16x16x32_bf16(
                        bfr[ni], af[ml], acc[ml][ni], 0, 0, 0);
        }

        if (more) {
            // free the buffer for restage (all waves done reading tile i)
            asm volatile("" ::: "memory");
            __builtin_amdgcn_s_barrier();
            asm volatile("" ::: "memory");
        }
    }

    // --- epilogue (swapped operands): lane holds 4 consecutive n at reg r --
    // m = wmoff + mi*16 + lrow ; n = wnoff + ni*16 + lgrp*4 + r
    const int wnoff = n0 + wn * (NF * 16);
    const int wmoff = m0 + wm * 128;
#pragma unroll
    for (int ni = 0; ni < NF; ++ni) {
        const int ncol = wnoff + ni * 16 + lgrp * 4;
        const float4 bv = *reinterpret_cast<const float4*>(&bias[ncol]);
#pragma unroll
        for (int mi = 0; mi < 8; ++mi) {
            const int row = wmoff + mi * 16 + lrow;
            float v0 = acc[mi][ni][0] + bv.x;
            float v1 = acc[mi][ni][1] + bv.y;
            float v2 = acc[mi][ni][2] + bv.z;
            float v3 = acc[mi][ni][3] + bv.w;
            if (RELU) {
                v0 = fmaxf(v0, 0.0f); v1 = fmaxf(v1, 0.0f);
                v2 = fmaxf(v2, 0.0f); v3 = fmaxf(v3, 0.0f);
            }
            const size_t base = (size_t)t * strideC + (size_t)row * N + ncol;
            if (OUTBF16) {
                uint2 p;
                p.x = (uint)f2bf(v0) | ((uint)f2bf(v1) << 16);
                p.y = (uint)f2bf(v2) | ((uint)f2bf(v3) << 16);
                *reinterpret_cast<uint2*>(&((ushort*)Cbase)[base]) = p;
            } else {
                float4 p = {v0, v1, v2, v3};
                *reinterpret_cast<float4*>(&((float*)Cbase)[base]) = p;
            }
        }
    }
}

extern "C" void kernel_launch(void* const* d_in, const int* in_sizes, int n_in,
                              void* d_out, int out_size, void* d_ws, size_t ws_size,
                              hipStream_t stream) {
    const float* x0 = (const float*)d_in[0];
    const float* x1 = (const float*)d_in[1];
    const float* x2 = (const float*)d_in[2];
    const float* x3 = (const float*)d_in[3];
    // d_in[4] = node_type (unused: nodes are blocked by type already)
    const float* W1 = (const float*)d_in[5];
    const float* b1 = (const float*)d_in[6];
    const float* W2[4] = {(const float*)d_in[7], (const float*)d_in[9],
                          (const float*)d_in[11], (const float*)d_in[13]};
    const float* b2[4] = {(const float*)d_in[8], (const float*)d_in[10],
                          (const float*)d_in[12], (const float*)d_in[14]};

    // workspace layout (bytes):
    //   H    bf16 [4][16384][1024]  134217728
    //   W1T  bf16 [4][1024][512]      4194304
    //   W2T  bf16 [4][128][1024]      1048576
    //   b2p  f32  [4][128]                2048
    char* ws = (char*)d_ws;
    ushort* H   = (ushort*)ws;
    ushort* W1T = (ushort*)(ws + 134217728ull);
    ushort* W2T = (ushort*)(ws + 134217728ull + 4194304ull);
    float*  b2p = (float*)(ws + 134217728ull + 4194304ull + 1048576ull);

    // weight conversions (small)
    cvt_w_t_kernel<<<dim3(32, 16, 4), 256, 0, stream>>>(
        W1, W1T, DIN, DH, (size_t)DIN * DH, (size_t)DH * DIN);
    cvt_w2_kernel<<<dim3(4, 32, 4), 256, 0, stream>>>(
        W2[0], W2[1], W2[2], W2[3], b2[0], b2[1], b2[2], b2[3], W2T, b2p);

    // layer 1: H = relu(X @ W1 + b1), fused fp32->bf16 A path, bf16 out
    // grid: 4 types x 64 m-tiles x 4 n-tiles = 1024 (n fastest: A L2 reuse)
    gemms<256, true, true, true><<<1024, 512, 0, stream>>>(
        x0, x1, x2, x3, W1T, b1, H,
        DH, DIN, NNODE / 256,
        0, (size_t)DH * DIN, (size_t)DH, (size_t)NNODE * DH);

    // layer 2: out = H @ W2 + b2 (padded cols exactly 0), fp32 out
    // grid: 4 types x 64 m-tiles x 1 n-tile = 256
    gemms<128, false, false, false><<<256, 512, 0, stream>>>(
        H, H, H, H, W2T, b2p, d_out,
        MAXO, DH, NNODE / 256,
        (size_t)NNODE * DH, (size_t)MAXO * DH, (size_t)MAXO,
        (size_t)NNODE * MAXO);
}

// Round 11
// 163.621 us; speedup vs baseline: 5.3528x; 5.3528x over previous
//
#include <hip/hip_runtime.h>
#include <hip/hip_bf16.h>

// ---------------------------------------------------------------------------
// QLayer: per-type 2-layer MLP.
//   h   = relu(x_t @ W1_t + b1_t)       [16384x512]@[512x1024]   (x4 types)
//   out = h @ W2_t + b2_t, padded to 128 cols                    (x4 types)
// Round 11: GEMM1 re-decomposed as persistent m-panel: each block owns 64
// rows and computes ALL N=1024 (X staged/converted once -> no 4x re-read,
// which was ~45us of r9's 129.7). W1 streamed through LDS in [512][64]
// halves (dbuf 2x64KB, L2-resident source); A k-tile dbuf 2x8KB with the
// r9 fa-pipeline (fused fp32->bf16). 16 iters/block, 1 barrier per iter.
// GEMM2 unchanged (r9 structure, at its memory floor).
// NOTE r10 lesson: __launch_bounds__ min-waves arg caps VGPRs -> spill; use 1.
// ---------------------------------------------------------------------------

typedef __attribute__((ext_vector_type(8))) short short8;
typedef __attribute__((ext_vector_type(4))) float f32x4;

#define NT 4
#define NNODE 16384
#define DIN 512
#define DH 1024
#define MAXO 128

static __device__ __forceinline__ ushort f2bf(float f) {
    __hip_bfloat16 h = __float2bfloat16(f);
    return *reinterpret_cast<ushort*>(&h);
}

static __device__ __forceinline__ short8 pack8(const float4 a, const float4 b) {
    union { short8 v; ushort u[8]; } r;
    r.u[0] = f2bf(a.x); r.u[1] = f2bf(a.y); r.u[2] = f2bf(a.z); r.u[3] = f2bf(a.w);
    r.u[4] = f2bf(b.x); r.u[5] = f2bf(b.y); r.u[6] = f2bf(b.z); r.u[7] = f2bf(b.w);
    return r.v;
}

#define GLD(gsrc, ldst)                                                        \
    __builtin_amdgcn_global_load_lds(                                          \
        (const __attribute__((address_space(1))) void*)(gsrc),                 \
        (__attribute__((address_space(3))) void*)(ldst), 16, 0, 0)

// --- W1 transpose+convert: in fp32 [R][Cin] -> out bf16 [Cout][R] ----------
__global__ __launch_bounds__(256) void cvt_w_t_kernel(
    const float* __restrict__ in, ushort* __restrict__ out,
    int R, int Cin, size_t in_tstride, size_t out_tstride) {
    __shared__ float tile[32][33];
    const int t = blockIdx.z;
    in += (size_t)t * in_tstride;
    out += (size_t)t * out_tstride;
    const int c0 = blockIdx.x * 32, r0 = blockIdx.y * 32;
    const int cx = threadIdx.x & 31;
    const int ry = threadIdx.x >> 5;   // 0..7
#pragma unroll
    for (int j = 0; j < 4; ++j) {
        int rr = ry + j * 8;
        int c = c0 + cx;
        tile[rr][cx] = (c < Cin) ? in[(size_t)(r0 + rr) * Cin + c] : 0.0f;
    }
    __syncthreads();
#pragma unroll
    for (int j = 0; j < 4; ++j) {
        int cc = ry + j * 8;
        out[(size_t)(c0 + cc) * R + r0 + cx] = f2bf(tile[cx][cc]);
    }
}

// --- W2 (all 4 types) transpose+convert + b2 pad, one launch ---------------
__global__ __launch_bounds__(256) void cvt_w2_kernel(
    const float* __restrict__ w0, const float* __restrict__ w1,
    const float* __restrict__ w2, const float* __restrict__ w3,
    const float* __restrict__ c0_, const float* __restrict__ c1_,
    const float* __restrict__ c2_, const float* __restrict__ c3_,
    ushort* __restrict__ out, float* __restrict__ b2p) {
    __shared__ float tile[32][33];
    const int t = blockIdx.z;
    const int Cin = (t == 0) ? 128 : (t == 1) ? 96 : (t == 2) ? 64 : 32;
    const float* in = (t == 0) ? w0 : (t == 1) ? w1 : (t == 2) ? w2 : w3;
    ushort* o = out + (size_t)t * MAXO * DH;
    const int c0 = blockIdx.x * 32, r0 = blockIdx.y * 32;
    const int cx = threadIdx.x & 31;
    const int ry = threadIdx.x >> 5;
#pragma unroll
    for (int j = 0; j < 4; ++j) {
        int rr = ry + j * 8;
        int c = c0 + cx;
        tile[rr][cx] = (c < Cin) ? in[(size_t)(r0 + rr) * Cin + c] : 0.0f;
    }
    __syncthreads();
#pragma unroll
    for (int j = 0; j < 4; ++j) {
        int cc = ry + j * 8;
        o[(size_t)(c0 + cc) * DH + r0 + cx] = f2bf(tile[cx][cc]);
    }
    if (blockIdx.x == 0 && blockIdx.y == 0 && threadIdx.x < 128) {
        const float* b = (t == 0) ? c0_ : (t == 1) ? c1_ : (t == 2) ? c2_ : c3_;
        const int n = threadIdx.x;
        b2p[t * 128 + n] = (n < Cin) ? b[n] : 0.0f;
    }
}

// ---------------------------------------------------------------------------
// GEMM1 persistent m-panel kernel: H = relu(X @ W1 + b1), per type.
// Block = 64 rows x ALL 1024 cols; grid = 4 types x 256 panels = 1024.
// 512 threads = 8 waves; wave w covers n = niG*128 + w*16 (niG 0..7) x 64 m.
// acc[4 ml][8 niG] f32x4 = 128 regs (swapped-operand MFMA: lane has 4 n).
//
// LDS (144 KB): Bbuf 2 x [512 rows][64 k] bf16 (64 KB each, dbuf over the
// 16 flat iters j = k*2+h; half h = n in [h*512,(h+1)*512)); Abuf 2 x 8 KB
// ([64][64] bf16 k-tile, dbuf over k). XOR swizzle both sides:
// byte(row,16B-chunk c) = row*128 + ((c*16) ^ ((row&7)<<4)).
//
// Per iter j (k=j>>1, h=j&1):
//   h==0: fa <- X fp32 for A(k+1)          (2 float4/thread, drained at end)
//   GLD B(iter j+1) -> Bbuf[(j+1)&1]       (8 GLD w16/thread, W1T from L2)
//   h==1: pack8+ds_write fa -> Abuf[(k+1)&1]  (issued 1 iter earlier)
//   compute: 2 kkk x {4 B-frags + 4 A-frags ds_read_b128; 16 MFMA}
//   vmcnt(0) lgkmcnt(0); s_barrier         (single sync point per iter)
// ---------------------------------------------------------------------------
__global__ __launch_bounds__(512, 1) void gemm1p(
    const float* __restrict__ x0, const float* __restrict__ x1,
    const float* __restrict__ x2, const float* __restrict__ x3,
    const ushort* __restrict__ W1T, const float* __restrict__ b1,
    ushort* __restrict__ H) {
    constexpr int K = DIN;                 // 512
    __shared__ char lds[147456];           // B 2x64KB @0, A 2x8KB @131072

    // XCD-bijective block swizzle (grid = 1024, %8 == 0)
    const int cpx = gridDim.x >> 3;
    const int g = blockIdx.x;
    const int wg = (g & 7) * cpx + (g >> 3);
    const int t = wg >> 8;                 // type
    const int m0 = (wg & 255) * 64;        // m-panel

    const float* Af = (t == 0) ? x0 : (t == 1) ? x1 : (t == 2) ? x2 : x3;
    const ushort* Bt = W1T + (size_t)t * DH * K;
    const float* bias = b1 + (size_t)t * DH;
    ushort* Ht = H + (size_t)t * NNODE * DH;

    const int tid = threadIdx.x;
    const int lane = tid & 63;
    const int w = tid >> 6;                // wave 0..7
    const int lrow = lane & 15, lgrp = lane >> 4;

    // A staging: 1 16B-chunk/thread per 8KB k-tile
    const int ar_ = tid >> 3, ac8 = tid & 7;
    const float* asrc = Af + (size_t)(m0 + ar_) * K + ac8 * 8;    // + k*64
    const int adst = ar_ * 128 + ((ac8 * 16) ^ ((ar_ & 7) << 4)); // + buf off

    // B staging: 8 chunks/thread per 64KB half ([512][64])
    const ushort* bsrc[8];
    int bdst[8];
#pragma unroll
    for (int j = 0; j < 8; ++j) {
        const int c = j * 512 + tid;       // chunk 0..4095
        const int r = c >> 3;              // local row 0..511
        const int cb = ((c & 7) * 16) ^ ((r & 7) << 4);
        bsrc[j] = Bt + (size_t)r * K + (cb >> 1);  // + (h*512)*K + k*64
        bdst[j] = c * 16;
    }

    f32x4 acc[4][8] = {};
    float4 fa0, fa1;

    // --- prologue: A(0) -> Abuf0, B(iter0 = k0,h0) -> Bbuf0 ----------------
    fa0 = *reinterpret_cast<const float4*>(asrc);
    fa1 = *reinterpret_cast<const float4*>(asrc + 4);
#pragma unroll
    for (int j = 0; j < 8; ++j) GLD(bsrc[j], lds + bdst[j]);
    asm volatile("s_waitcnt vmcnt(8)" ::: "memory");   // fa landed
    *reinterpret_cast<short8*>(lds + 131072 + adst) = pack8(fa0, fa1);
    asm volatile("s_waitcnt vmcnt(0) lgkmcnt(0)" ::: "memory");
    __builtin_amdgcn_s_barrier();
    asm volatile("" ::: "memory");

#pragma unroll
    for (int j = 0; j < 16; ++j) {
        const int k = j >> 1, h = j & 1;

        // fa <- X(k+1) fp32 at h==0 (consumed by ds_write next iter)
        if (h == 0 && k + 1 < 8) {
            fa0 = *reinterpret_cast<const float4*>(asrc + (k + 1) * 64);
            fa1 = *reinterpret_cast<const float4*>(asrc + (k + 1) * 64 + 4);
        }
        // stage B for iter j+1
        if (j + 1 < 16) {
            const int k2 = (j + 1) >> 1, h2 = (j + 1) & 1;
            const size_t off = (size_t)(h2 * 512) * K + k2 * 64;
            char* nb = lds + ((j + 1) & 1) * 65536;
#pragma unroll
            for (int jj = 0; jj < 8; ++jj) GLD(bsrc[jj] + off, nb + bdst[jj]);
        }
        // publish A(k+1) at h==1 (fa loaded a full iter ago)
        if (h == 1 && k + 1 < 8)
            *reinterpret_cast<short8*>(
                lds + 131072 + ((k + 1) & 1) * 8192 + adst) = pack8(fa0, fa1);

        // compute iter j: Bbuf[j&1] (half h of k-tile k), Abuf[k&1]
        const char* Bl = lds + (j & 1) * 65536;
        const char* Al = lds + 131072 + (k & 1) * 8192;
#pragma unroll
        for (int kkk = 0; kkk < 2; ++kkk) {
            short8 bfr[4], af[4];
#pragma unroll
            for (int ni = 0; ni < 4; ++ni) {
                const int br = ni * 128 + w * 16 + lrow;   // local row in half
                const int kb = (kkk * 64 + lgrp * 16) ^ ((br & 7) << 4);
                bfr[ni] = *(const short8*)(Bl + br * 128 + kb);
            }
#pragma unroll
            for (int ml = 0; ml < 4; ++ml) {
                const int ar = ml * 16 + lrow;
                const int kb = (kkk * 64 + lgrp * 16) ^ ((ar & 7) << 4);
                af[ml] = *(const short8*)(Al + ar * 128 + kb);
            }
#pragma unroll
            for (int ml = 0; ml < 4; ++ml)
#pragma unroll
                for (int ni = 0; ni < 4; ++ni)
                    acc[ml][h * 4 + ni] = __builtin_amdgcn_mfma_f32_16x16x32_bf16(
                        bfr[ni], af[ml], acc[ml][h * 4 + ni], 0, 0, 0);
        }

        if (j + 1 < 16) {
            asm volatile("s_waitcnt vmcnt(0) lgkmcnt(0)" ::: "memory");
            __builtin_amdgcn_s_barrier();
            asm volatile("" ::: "memory");
        }
    }

    // --- epilogue: lane holds 4 consecutive n; m = ml*16+lrow --------------
#pragma unroll
    for (int niG = 0; niG < 8; ++niG) {
        const int ncol = niG * 128 + w * 16 + lgrp * 4;
        const float4 bv = *reinterpret_cast<const float4*>(&bias[ncol]);
#pragma unroll
        for (int ml = 0; ml < 4; ++ml) {
            const int row = m0 + ml * 16 + lrow;
            float v0 = fmaxf(acc[ml][niG][0] + bv.x, 0.0f);
            float v1 = fmaxf(acc[ml][niG][1] + bv.y, 0.0f);
            float v2 = fmaxf(acc[ml][niG][2] + bv.z, 0.0f);
            float v3 = fmaxf(acc[ml][niG][3] + bv.w, 0.0f);
            uint2 p;
            p.x = (uint)f2bf(v0) | ((uint)f2bf(v1) << 16);
            p.y = (uint)f2bf(v2) | ((uint)f2bf(v3) << 16);
            *reinterpret_cast<uint2*>(&Ht[(size_t)row * DH + ncol]) = p;
        }
    }
}

// ---------------------------------------------------------------------------
// GEMM2 (r9 structure, unchanged): out = H @ W2T^T + b2, BM=256, BN=128,
// BK=64 dbuf, 1 barrier/K-tile, global_load_lds staging, XOR swizzle.
// ---------------------------------------------------------------------------
__global__ __launch_bounds__(512, 1) void gemm2k(
    const ushort* __restrict__ Hbase, const ushort* __restrict__ Bbase,
    const float* __restrict__ biasbase, float* __restrict__ Cbase,
    int N, int K, int MT) {
    constexpr int NF = 2;                  // BN=128
    constexpr int NBC = 2;
    constexpr int ABYTES = 256 * 64 * 2;   // 32 KB
    constexpr int BBYTES = 128 * 64 * 2;   // 16 KB
    constexpr int BUF = ABYTES + BBYTES;
    __shared__ char lds[2 * BUF];

    const int cpx = gridDim.x >> 3;
    const int g = blockIdx.x;
    const int wg = (g & 7) * cpx + (g >> 3);
    const int t = wg / MT;
    const int m0 = (wg % MT) * 256;

    const ushort* A = Hbase + (size_t)t * NNODE * DH;
    const ushort* Bp = Bbase + (size_t)t * MAXO * DH;
    const float* bias = biasbase + (size_t)t * MAXO;

    const int tid = threadIdx.x;
    const int lane = tid & 63;
    const int w = tid >> 6;
    const int wm = w >> 2, wn = w & 3;
    const int lrow = lane & 15, lgrp = lane >> 4;

    const ushort* abfsrc[4];
    int adst[4];
#pragma unroll
    for (int j = 0; j < 4; ++j) {
        const int c = j * 512 + tid;
        const int r = c >> 3;
        const int cb = ((c & 7) * 16) ^ ((r & 7) << 4);
        abfsrc[j] = A + (size_t)(m0 + r) * K + (cb >> 1);
        adst[j] = c * 16;
    }
    const ushort* bsrc[NBC];
    int bdst[NBC];
#pragma unroll
    for (int j = 0; j < NBC; ++j) {
        const int c = j * 512 + tid;
        const int r = c >> 3;
        const int cb = ((c & 7) * 16) ^ ((r & 7) << 4);
        bsrc[j] = Bp + (size_t)r * K + (cb >> 1);
        bdst[j] = ABYTES + c * 16;
    }

    f32x4 acc[8][NF] = {};
    const int NK = K / 64;

#pragma unroll
    for (int j = 0; j < 4; ++j) GLD(abfsrc[j], lds + adst[j]);
#pragma unroll
    for (int j = 0; j < NBC; ++j) GLD(bsrc[j], lds + bdst[j]);
    asm volatile("s_waitcnt vmcnt(0)" ::: "memory");
    __builtin_amdgcn_s_barrier();
    asm volatile("" ::: "memory");

    for (int i = 0; i < NK; ++i) {
        const char* cu_ = lds + (i & 1) * BUF;
        char* nx_ = lds + ((i + 1) & 1) * BUF;
        const int ktn = (i + 1) * 64;
        const bool st = (i + 1 < NK);

        if (st) {
#pragma unroll
            for (int j = 0; j < 4; ++j) GLD(abfsrc[j] + ktn, nx_ + adst[j]);
#pragma unroll
            for (int j = 0; j < NBC; ++j) GLD(bsrc[j] + ktn, nx_ + bdst[j]);
        }

#pragma unroll
        for (int kkk = 0; kkk < 2; ++kkk) {
            short8 bfr[NF], af[8];
#pragma unroll
            for (int ni = 0; ni < NF; ++ni) {
                const int br = wn * (NF * 16) + ni * 16 + lrow;
                const int kb = (kkk * 64 + lgrp * 16) ^ ((br & 7) << 4);
                bfr[ni] = *(const short8*)(cu_ + ABYTES + br * 128 + kb);
            }
#pragma unroll
            for (int ml = 0; ml < 8; ++ml) {
                const int ar = wm * 128 + ml * 16 + lrow;
                const int kb = (kkk * 64 + lgrp * 16) ^ ((ar & 7) << 4);
                af[ml] = *(const short8*)(cu_ + ar * 128 + kb);
            }
#pragma unroll
            for (int ml = 0; ml < 8; ++ml)
#pragma unroll
                for (int ni = 0; ni < NF; ++ni)
                    acc[ml][ni] = __builtin_amdgcn_mfma_f32_16x16x32_bf16(
                        bfr[ni], af[ml], acc[ml][ni], 0, 0, 0);
        }

        if (st) {
            asm volatile("s_waitcnt vmcnt(0)" ::: "memory");
            __builtin_amdgcn_s_barrier();
            asm volatile("" ::: "memory");
        }
    }

    const int wnoff = wn * (NF * 16);
    const int wmoff = m0 + wm * 128;
#pragma unroll
    for (int ni = 0; ni < NF; ++ni) {
        const int ncol = wnoff + ni * 16 + lgrp * 4;
        const float4 bv = *reinterpret_cast<const float4*>(&bias[ncol]);
#pragma unroll
        for (int mi = 0; mi < 8; ++mi) {
            const int row = wmoff + mi * 16 + lrow;
            float4 p;
            p.x = acc[mi][ni][0] + bv.x;
            p.y = acc[mi][ni][1] + bv.y;
            p.z = acc[mi][ni][2] + bv.z;
            p.w = acc[mi][ni][3] + bv.w;
            *reinterpret_cast<float4*>(
                &Cbase[(size_t)t * NNODE * MAXO + (size_t)row * N + ncol]) = p;
        }
    }
}

extern "C" void kernel_launch(void* const* d_in, const int* in_sizes, int n_in,
                              void* d_out, int out_size, void* d_ws, size_t ws_size,
                              hipStream_t stream) {
    const float* x0 = (const float*)d_in[0];
    const float* x1 = (const float*)d_in[1];
    const float* x2 = (const float*)d_in[2];
    const float* x3 = (const float*)d_in[3];
    // d_in[4] = node_type (unused: nodes are blocked by type already)
    const float* W1 = (const float*)d_in[5];
    const float* b1 = (const float*)d_in[6];
    const float* W2[4] = {(const float*)d_in[7], (const float*)d_in[9],
                          (const float*)d_in[11], (const float*)d_in[13]};
    const float* b2[4] = {(const float*)d_in[8], (const float*)d_in[10],
                          (const float*)d_in[12], (const float*)d_in[14]};

    // workspace layout (bytes):
    //   H    bf16 [4][16384][1024]  134217728
    //   W1T  bf16 [4][1024][512]      4194304
    //   W2T  bf16 [4][128][1024]      1048576
    //   b2p  f32  [4][128]                2048
    char* ws = (char*)d_ws;
    ushort* H   = (ushort*)ws;
    ushort* W1T = (ushort*)(ws + 134217728ull);
    ushort* W2T = (ushort*)(ws + 134217728ull + 4194304ull);
    float*  b2p = (float*)(ws + 134217728ull + 4194304ull + 1048576ull);

    // weight conversions (small)
    cvt_w_t_kernel<<<dim3(32, 16, 4), 256, 0, stream>>>(
        W1, W1T, DIN, DH, (size_t)DIN * DH, (size_t)DH * DIN);
    cvt_w2_kernel<<<dim3(4, 32, 4), 256, 0, stream>>>(
        W2[0], W2[1], W2[2], W2[3], b2[0], b2[1], b2[2], b2[3], W2T, b2p);

    // layer 1: persistent m-panel GEMM, X read once, fused fp32->bf16
    // grid: 4 types x 256 panels = 1024
    gemm1p<<<1024, 512, 0, stream>>>(x0, x1, x2, x3, W1T, b1, H);

    // layer 2: out = H @ W2 + b2 (padded cols exactly 0), fp32 out
    // grid: 4 types x 64 m-tiles = 256
    gemm2k<<<256, 512, 0, stream>>>(H, W2T, b2p, (float*)d_out,
                                    MAXO, DH, NNODE / 256);
}